// Round 1
// baseline (490.819 us; speedup 1.0000x reference)
//
#include <hip/hip_runtime.h>

#define N_NODES 50000
#define N_EDGES 800000
#define D 64

// srcdata = feat @ W_neigh^T   (W_neigh is [D_OUT, D_IN] row-major)
// 256 threads: 4 rows per block, 64 threads (one wave) per row, one col each.
__global__ void gemm_neigh_kernel(const float* __restrict__ feat,
                                  const float* __restrict__ Wn,
                                  float* __restrict__ srcdata) {
    __shared__ float Ws[D * D]; // Ws[k*D + c] = Wn[c*D + k]  (transposed for conflict-free reads)
    int t = threadIdx.x;
    for (int i = t; i < D * D; i += 256) {
        int c = i >> 6, k = i & 63;
        Ws[k * D + c] = Wn[c * D + k];
    }
    __syncthreads();
    int r = blockIdx.x * 4 + (t >> 6);
    int c = t & 63;
    if (r >= N_NODES) return;
    const float* f = feat + r * D;
    float sum = 0.f;
#pragma unroll
    for (int k = 0; k < D; ++k) sum += f[k] * Ws[k * D + c];
    srcdata[r * D + c] = sum;
}

// One wave (64 lanes) per edge; 4 edges per 256-thread block.
__global__ void scatter_kernel(const int* __restrict__ src,
                               const int* __restrict__ dst,
                               const float* __restrict__ srcdata,
                               float* __restrict__ agg,
                               float* __restrict__ deg) {
    int t = threadIdx.x;
    int e = blockIdx.x * 4 + (t >> 6);
    if (e >= N_EDGES) return;
    int c = t & 63;
    int s = src[e];
    int d = dst[e];
    float v = srcdata[s * D + c];
    atomicAdd(&agg[d * D + c], v);
    if (c == 0) atomicAdd(&deg[d], 1.0f);
}

// out = feat @ W_self^T + b + (deg>0 ? agg/deg : 0)
__global__ void epilogue_kernel(const float* __restrict__ feat,
                                const float* __restrict__ Wself,
                                const float* __restrict__ b,
                                const float* __restrict__ agg,
                                const float* __restrict__ deg,
                                float* __restrict__ out) {
    __shared__ float Ws[D * D];
    int t = threadIdx.x;
    for (int i = t; i < D * D; i += 256) {
        int c = i >> 6, k = i & 63;
        Ws[k * D + c] = Wself[c * D + k];
    }
    __syncthreads();
    int r = blockIdx.x * 4 + (t >> 6);
    int c = t & 63;
    if (r >= N_NODES) return;
    const float* f = feat + r * D;
    float sum = b[c];
#pragma unroll
    for (int k = 0; k < D; ++k) sum += f[k] * Ws[k * D + c];
    float dg = deg[r];
    float ds = (dg > 0.f) ? (agg[r * D + c] / dg) : 0.f;
    out[r * D + c] = sum + ds;
}

extern "C" void kernel_launch(void* const* d_in, const int* in_sizes, int n_in,
                              void* d_out, int out_size, void* d_ws, size_t ws_size,
                              hipStream_t stream) {
    const float* feat  = (const float*)d_in[0];
    const int*   src   = (const int*)d_in[1];
    const int*   dst   = (const int*)d_in[2];
    const float* Wn    = (const float*)d_in[3];
    const float* Wself = (const float*)d_in[4];
    const float* bself = (const float*)d_in[5];
    float* out = (float*)d_out;

    float* srcdata = (float*)d_ws;                 // N_NODES * D
    float* agg     = srcdata + (size_t)N_NODES * D; // N_NODES * D
    float* deg     = agg + (size_t)N_NODES * D;     // N_NODES

    // agg + deg must start at zero every call (d_ws is poisoned 0xAA).
    hipMemsetAsync(agg, 0, ((size_t)N_NODES * D + N_NODES) * sizeof(float), stream);

    gemm_neigh_kernel<<<(N_NODES + 3) / 4, 256, 0, stream>>>(feat, Wn, srcdata);
    scatter_kernel<<<(N_EDGES + 3) / 4, 256, 0, stream>>>(src, dst, srcdata, agg, deg);
    epilogue_kernel<<<(N_NODES + 3) / 4, 256, 0, stream>>>(feat, Wself, bself, agg, deg, out);
}

// Round 2
// 432.904 us; speedup vs baseline: 1.1338x; 1.1338x over previous
//
#include <hip/hip_runtime.h>

#define N_NODES 50000
#define N_EDGES 800000
#define D 64
#define LDW 65   // LDS leading dim: bank = (k + c) % 32 -> conflict-free
#define NB 196   // ceil(N_NODES / 256)

// srcdata = feat @ W_neigh^T
__global__ void gemm_neigh_kernel(const float* __restrict__ feat,
                                  const float* __restrict__ Wn,
                                  float* __restrict__ srcdata) {
    __shared__ float Ws[D * LDW];
    int t = threadIdx.x;
    for (int i = t; i < D * D; i += 256) {
        int c = i >> 6, k = i & 63;
        Ws[k * LDW + c] = Wn[c * D + k];
    }
    __syncthreads();
    int r = blockIdx.x * 4 + (t >> 6);
    int c = t & 63;
    if (r >= N_NODES) return;
    const float4* f4 = (const float4*)(feat + (size_t)r * D);
    float sum = 0.f;
#pragma unroll
    for (int kk = 0; kk < D / 4; ++kk) {
        float4 fv = f4[kk];
        sum += fv.x * Ws[(4 * kk + 0) * LDW + c];
        sum += fv.y * Ws[(4 * kk + 1) * LDW + c];
        sum += fv.z * Ws[(4 * kk + 2) * LDW + c];
        sum += fv.w * Ws[(4 * kk + 3) * LDW + c];
    }
    srcdata[(size_t)r * D + c] = sum;
}

__global__ void hist_kernel(const int* __restrict__ dst, int* __restrict__ hist) {
    int e = blockIdx.x * 256 + threadIdx.x;
    if (e < N_EDGES) atomicAdd(&hist[dst[e]], 1);
}

// Per-256-chunk exclusive scan; chunk totals to bsum.
__global__ void scan1_kernel(const int* __restrict__ hist, int* __restrict__ offs,
                             int* __restrict__ bsum) {
    __shared__ int s[256];
    int tid = threadIdx.x;
    int i = blockIdx.x * 256 + tid;
    int v = (i < N_NODES) ? hist[i] : 0;
    s[tid] = v;
    __syncthreads();
    for (int d = 1; d < 256; d <<= 1) {
        int t_ = (tid >= d) ? s[tid - d] : 0;
        __syncthreads();
        s[tid] += t_;
        __syncthreads();
    }
    if (i < N_NODES) offs[i] = s[tid] - v;      // exclusive
    if (tid == 255) bsum[blockIdx.x] = s[255];  // chunk total
}

// Exclusive scan of the NB chunk totals (single block).
__global__ void scan2_kernel(int* __restrict__ bsum) {
    __shared__ int s[256];
    int tid = threadIdx.x;
    int v = (tid < NB) ? bsum[tid] : 0;
    s[tid] = v;
    __syncthreads();
    for (int d = 1; d < 256; d <<= 1) {
        int t_ = (tid >= d) ? s[tid - d] : 0;
        __syncthreads();
        s[tid] += t_;
        __syncthreads();
    }
    if (tid < NB) bsum[tid] = s[tid] - v;
}

__global__ void addoff_kernel(int* __restrict__ offs, const int* __restrict__ bsum,
                              int* __restrict__ cursor) {
    int i = blockIdx.x * 256 + threadIdx.x;
    if (i < N_NODES) {
        int v = offs[i] + bsum[blockIdx.x];
        offs[i] = v;
        cursor[i] = v;
    }
}

__global__ void fill_kernel(const int* __restrict__ src, const int* __restrict__ dst,
                            int* __restrict__ cursor, int* __restrict__ esrc) {
    int e = blockIdx.x * 256 + threadIdx.x;
    if (e < N_EDGES) {
        int p = atomicAdd(&cursor[dst[e]], 1);
        esrc[p] = src[e];
    }
}

// out[r] = fc_self(feat[r]) + mean over in-edges of srcdata[src]
// One wave per dst node; lane = output column.
__global__ void gather_epi_kernel(const float* __restrict__ feat,
                                  const float* __restrict__ Wself,
                                  const float* __restrict__ bias,
                                  const float* __restrict__ srcdata,
                                  const int* __restrict__ offs,
                                  const int* __restrict__ hist,
                                  const int* __restrict__ esrc,
                                  float* __restrict__ out) {
    __shared__ float Ws[D * LDW];
    int t = threadIdx.x;
    for (int i = t; i < D * D; i += 256) {
        int c = i >> 6, k = i & 63;
        Ws[k * LDW + c] = Wself[c * D + k];
    }
    __syncthreads();
    int r = blockIdx.x * 4 + (t >> 6);
    int c = t & 63;
    if (r >= N_NODES) return;
    const float4* f4 = (const float4*)(feat + (size_t)r * D);
    float self = bias[c];
#pragma unroll
    for (int kk = 0; kk < D / 4; ++kk) {
        float4 fv = f4[kk];
        self += fv.x * Ws[(4 * kk + 0) * LDW + c];
        self += fv.y * Ws[(4 * kk + 1) * LDW + c];
        self += fv.z * Ws[(4 * kk + 2) * LDW + c];
        self += fv.w * Ws[(4 * kk + 3) * LDW + c];
    }
    int deg = hist[r];
    int start = offs[r];
    float acc = 0.f;
    int i = 0;
    // 8 independent loads in flight per iteration to hide gather latency.
    for (; i + 8 <= deg; i += 8) {
        int id = (c < 8) ? esrc[start + i + c] : 0;
        int s0 = __shfl(id, 0), s1 = __shfl(id, 1), s2 = __shfl(id, 2), s3 = __shfl(id, 3);
        int s4 = __shfl(id, 4), s5 = __shfl(id, 5), s6 = __shfl(id, 6), s7 = __shfl(id, 7);
        acc += srcdata[(size_t)s0 * D + c];
        acc += srcdata[(size_t)s1 * D + c];
        acc += srcdata[(size_t)s2 * D + c];
        acc += srcdata[(size_t)s3 * D + c];
        acc += srcdata[(size_t)s4 * D + c];
        acc += srcdata[(size_t)s5 * D + c];
        acc += srcdata[(size_t)s6 * D + c];
        acc += srcdata[(size_t)s7 * D + c];
    }
    for (; i < deg; ++i) {
        int s = esrc[start + i];
        acc += srcdata[(size_t)s * D + c];
    }
    out[(size_t)r * D + c] = self + (deg > 0 ? acc / (float)deg : 0.f);
}

extern "C" void kernel_launch(void* const* d_in, const int* in_sizes, int n_in,
                              void* d_out, int out_size, void* d_ws, size_t ws_size,
                              hipStream_t stream) {
    const float* feat  = (const float*)d_in[0];
    const int*   src   = (const int*)d_in[1];
    const int*   dst   = (const int*)d_in[2];
    const float* Wn    = (const float*)d_in[3];
    const float* Wself = (const float*)d_in[4];
    const float* bself = (const float*)d_in[5];
    float* out = (float*)d_out;

    float* srcdata = (float*)d_ws;                       // N_NODES*D floats (12.8 MB)
    int* hist   = (int*)(srcdata + (size_t)N_NODES * D); // N_NODES
    int* offs   = hist + N_NODES;                        // N_NODES
    int* cursor = offs + N_NODES;                        // N_NODES
    int* bsum   = cursor + N_NODES;                      // 256
    int* esrc   = bsum + 256;                            // N_EDGES

    hipMemsetAsync(hist, 0, (size_t)N_NODES * sizeof(int), stream);

    gemm_neigh_kernel<<<(N_NODES + 3) / 4, 256, 0, stream>>>(feat, Wn, srcdata);
    hist_kernel<<<(N_EDGES + 255) / 256, 256, 0, stream>>>(dst, hist);
    scan1_kernel<<<NB, 256, 0, stream>>>(hist, offs, bsum);
    scan2_kernel<<<1, 256, 0, stream>>>(bsum);
    addoff_kernel<<<NB, 256, 0, stream>>>(offs, bsum, cursor);
    fill_kernel<<<(N_EDGES + 255) / 256, 256, 0, stream>>>(src, dst, cursor, esrc);
    gather_epi_kernel<<<(N_NODES + 3) / 4, 256, 0, stream>>>(
        feat, Wself, bself, srcdata, offs, hist, esrc, out);
}

// Round 3
// 208.422 us; speedup vs baseline: 2.3549x; 2.0771x over previous
//
#include <hip/hip_runtime.h>

#define N_NODES 50000
#define N_EDGES 800000
#define D 64
#define NB 196   // ceil(N_NODES/256)

typedef __attribute__((ext_vector_type(8))) __bf16 bf16x8;
typedef __attribute__((ext_vector_type(4))) float f32x4;

__device__ inline float bflo(unsigned u) { unsigned x = u << 16; return __builtin_bit_cast(float, x); }
__device__ inline float bfhi(unsigned u) { unsigned x = u & 0xffff0000u; return __builtin_bit_cast(float, x); }
__device__ inline unsigned f2bf(float f) {  // round-to-nearest-even, returns in low 16
    unsigned b = __builtin_bit_cast(unsigned, f);
    b += 0x7fffu + ((b >> 16) & 1u);
    return b >> 16;
}

// ---- prep: fp32 -> bf16 conversions ----
__global__ void cvt_feat_kernel(const float* __restrict__ feat, unsigned short* __restrict__ fb) {
    int t = blockIdx.x * 256 + threadIdx.x;
    if (t >= N_NODES * D / 4) return;
    float4 v = ((const float4*)feat)[t];
    uint2 o;
    o.x = f2bf(v.x) | (f2bf(v.y) << 16);
    o.y = f2bf(v.z) | (f2bf(v.w) << 16);
    ((uint2*)fb)[t] = o;
}

__global__ void cvt_w_kernel(const float* __restrict__ Wn, const float* __restrict__ Ws,
                             unsigned short* __restrict__ wnb, unsigned short* __restrict__ wsb) {
    int t = blockIdx.x * 256 + threadIdx.x;
    if (t < D * D) {
        wnb[t] = (unsigned short)f2bf(Wn[t]);
        wsb[t] = (unsigned short)f2bf(Ws[t]);
    }
}

// ---- CSR build ----
__global__ void hist_kernel(const int* __restrict__ dst, int* __restrict__ hist) {
    int e = blockIdx.x * 256 + threadIdx.x;
    if (e < N_EDGES) atomicAdd(&hist[dst[e]], 1);
}

__global__ void scan1_kernel(const int* __restrict__ hist, int* __restrict__ cursor,
                             int* __restrict__ bsum) {
    __shared__ int s[256];
    int tid = threadIdx.x;
    int i = blockIdx.x * 256 + tid;
    int v = (i < N_NODES) ? hist[i] : 0;
    s[tid] = v;
    __syncthreads();
    for (int d = 1; d < 256; d <<= 1) {
        int t_ = (tid >= d) ? s[tid - d] : 0;
        __syncthreads();
        s[tid] += t_;
        __syncthreads();
    }
    if (i < N_NODES) cursor[i] = s[tid] - v;    // exclusive within chunk
    if (tid == 255) bsum[blockIdx.x] = s[255];
}

__global__ void scan2_kernel(int* __restrict__ bsum) {
    __shared__ int s[256];
    int tid = threadIdx.x;
    int v = (tid < NB) ? bsum[tid] : 0;
    s[tid] = v;
    __syncthreads();
    for (int d = 1; d < 256; d <<= 1) {
        int t_ = (tid >= d) ? s[tid - d] : 0;
        __syncthreads();
        s[tid] += t_;
        __syncthreads();
    }
    if (tid < NB) bsum[tid] = s[tid] - v;
}

__global__ void addoff_kernel(int* __restrict__ cursor, const int* __restrict__ bsum) {
    int i = blockIdx.x * 256 + threadIdx.x;
    if (i < N_NODES) cursor[i] += bsum[blockIdx.x];
}

__global__ void fill_kernel(const int* __restrict__ src, const int* __restrict__ dst,
                            int* __restrict__ cursor, int* __restrict__ esrc) {
    int e = blockIdx.x * 256 + threadIdx.x;
    if (e < N_EDGES) {
        int p = atomicAdd(&cursor[dst[e]], 1);
        esrc[p] = src[e];
    }
}

// ---- gather: aggmean_bf16[r] = mean over in-edges of featbf[src] ----
// One wave per node. Lane = (es = lane>>3 edge-slot, p = lane&7 16B piece).
// One dwordx4 covers 8 edges' worth of row data (1 KB / instruction).
__global__ __launch_bounds__(256) void gather_kernel(
        const unsigned short* __restrict__ fb, const int* __restrict__ cursor,
        const int* __restrict__ hist, const int* __restrict__ esrc,
        unsigned short* __restrict__ aggb) {
    int r = blockIdx.x * 4 + (threadIdx.x >> 6);
    if (r >= N_NODES) return;
    int lane = threadIdx.x & 63;
    int es = lane >> 3, p = lane & 7;
    int deg = hist[r];
    int start = cursor[r] - deg;   // cursor was advanced to end by fill
    float acc[8] = {0.f, 0.f, 0.f, 0.f, 0.f, 0.f, 0.f, 0.f};
    int i = 0;
    for (; i + 16 <= deg; i += 16) {
        int id0 = esrc[start + i + es];
        int id1 = esrc[start + i + 8 + es];
        uint4 v0 = *(const uint4*)(fb + (size_t)id0 * D + p * 8);
        uint4 v1 = *(const uint4*)(fb + (size_t)id1 * D + p * 8);
        acc[0] += bflo(v0.x); acc[1] += bfhi(v0.x);
        acc[2] += bflo(v0.y); acc[3] += bfhi(v0.y);
        acc[4] += bflo(v0.z); acc[5] += bfhi(v0.z);
        acc[6] += bflo(v0.w); acc[7] += bfhi(v0.w);
        acc[0] += bflo(v1.x); acc[1] += bfhi(v1.x);
        acc[2] += bflo(v1.y); acc[3] += bfhi(v1.y);
        acc[4] += bflo(v1.z); acc[5] += bfhi(v1.z);
        acc[6] += bflo(v1.w); acc[7] += bfhi(v1.w);
    }
    for (; i + 8 <= deg; i += 8) {
        int id = esrc[start + i + es];
        uint4 v = *(const uint4*)(fb + (size_t)id * D + p * 8);
        acc[0] += bflo(v.x); acc[1] += bfhi(v.x);
        acc[2] += bflo(v.y); acc[3] += bfhi(v.y);
        acc[4] += bflo(v.z); acc[5] += bfhi(v.z);
        acc[6] += bflo(v.w); acc[7] += bfhi(v.w);
    }
    int rem = deg - i;
    if (es < rem) {
        int id = esrc[start + i + es];
        uint4 v = *(const uint4*)(fb + (size_t)id * D + p * 8);
        acc[0] += bflo(v.x); acc[1] += bfhi(v.x);
        acc[2] += bflo(v.y); acc[3] += bfhi(v.y);
        acc[4] += bflo(v.z); acc[5] += bfhi(v.z);
        acc[6] += bflo(v.w); acc[7] += bfhi(v.w);
    }
    // reduce over edge-slots (lanes differing in bits 3..5)
#pragma unroll
    for (int m = 8; m <= 32; m <<= 1) {
#pragma unroll
        for (int j = 0; j < 8; ++j) acc[j] += __shfl_xor(acc[j], m);
    }
    if (es == 0) {
        float inv = (deg > 0) ? 1.0f / (float)deg : 0.f;
        uint4 o;
        o.x = f2bf(acc[0] * inv) | (f2bf(acc[1] * inv) << 16);
        o.y = f2bf(acc[2] * inv) | (f2bf(acc[3] * inv) << 16);
        o.z = f2bf(acc[4] * inv) | (f2bf(acc[5] * inv) << 16);
        o.w = f2bf(acc[6] * inv) | (f2bf(acc[7] * inv) << 16);
        *(uint4*)(aggb + (size_t)r * D + p * 8) = o;
    }
}

// ---- fused dual-GEMM epilogue via MFMA ----
// out = featbf @ Wsbf^T + aggbf @ Wnbf^T + bias ; 16 nodes per wave.
__global__ __launch_bounds__(256) void mfma_epi_kernel(
        const unsigned short* __restrict__ fb, const unsigned short* __restrict__ aggb,
        const unsigned short* __restrict__ wsb, const unsigned short* __restrict__ wnb,
        const float* __restrict__ bias, float* __restrict__ out) {
    int wave = (blockIdx.x * 256 + threadIdx.x) >> 6;
    if (wave >= N_NODES / 16) return;   // 3125 waves exactly
    int lane = threadIdx.x & 63;
    int m = lane & 15, quad = lane >> 4;
    int r0 = wave * 16;
    // A fragments: A[m][k], k = q*32 + quad*8 + j
    bf16x8 aS0 = *(const bf16x8*)(fb   + (size_t)(r0 + m) * D + 0  + quad * 8);
    bf16x8 aS1 = *(const bf16x8*)(fb   + (size_t)(r0 + m) * D + 32 + quad * 8);
    bf16x8 aA0 = *(const bf16x8*)(aggb + (size_t)(r0 + m) * D + 0  + quad * 8);
    bf16x8 aA1 = *(const bf16x8*)(aggb + (size_t)(r0 + m) * D + 32 + quad * 8);
#pragma unroll
    for (int t = 0; t < 4; ++t) {   // output column tiles of 16
        // B fragments: B[k][n] = W[n][k], n = 16t + m
        bf16x8 bS0 = *(const bf16x8*)(wsb + (size_t)(16 * t + m) * D + 0  + quad * 8);
        bf16x8 bS1 = *(const bf16x8*)(wsb + (size_t)(16 * t + m) * D + 32 + quad * 8);
        bf16x8 bN0 = *(const bf16x8*)(wnb + (size_t)(16 * t + m) * D + 0  + quad * 8);
        bf16x8 bN1 = *(const bf16x8*)(wnb + (size_t)(16 * t + m) * D + 32 + quad * 8);
        f32x4 acc = {0.f, 0.f, 0.f, 0.f};
        acc = __builtin_amdgcn_mfma_f32_16x16x32_bf16(aS0, bS0, acc, 0, 0, 0);
        acc = __builtin_amdgcn_mfma_f32_16x16x32_bf16(aS1, bS1, acc, 0, 0, 0);
        acc = __builtin_amdgcn_mfma_f32_16x16x32_bf16(aA0, bN0, acc, 0, 0, 0);
        acc = __builtin_amdgcn_mfma_f32_16x16x32_bf16(aA1, bN1, acc, 0, 0, 0);
        float bv = bias[16 * t + m];
        // C/D: col = lane&15, row = quad*4 + reg
#pragma unroll
        for (int reg = 0; reg < 4; ++reg) {
            out[(size_t)(r0 + quad * 4 + reg) * D + 16 * t + m] = acc[reg] + bv;
        }
    }
}

extern "C" void kernel_launch(void* const* d_in, const int* in_sizes, int n_in,
                              void* d_out, int out_size, void* d_ws, size_t ws_size,
                              hipStream_t stream) {
    const float* feat  = (const float*)d_in[0];
    const int*   src   = (const int*)d_in[1];
    const int*   dst   = (const int*)d_in[2];
    const float* Wn    = (const float*)d_in[3];
    const float* Wself = (const float*)d_in[4];
    const float* bself = (const float*)d_in[5];
    float* out = (float*)d_out;

    unsigned short* featb = (unsigned short*)d_ws;                 // N*D bf16 (6.4 MB)
    unsigned short* aggb  = featb + (size_t)N_NODES * D;           // N*D bf16 (6.4 MB)
    unsigned short* wnb   = aggb + (size_t)N_NODES * D;            // 4096
    unsigned short* wsb   = wnb + D * D;                           // 4096
    int* hist   = (int*)(wsb + D * D);                             // N
    int* cursor = hist + N_NODES;                                  // N
    int* bsum   = cursor + N_NODES;                                // 256
    int* esrc   = bsum + 256;                                      // E (3.2 MB)

    hipMemsetAsync(hist, 0, (size_t)N_NODES * sizeof(int), stream);

    cvt_feat_kernel<<<(N_NODES * D / 4 + 255) / 256, 256, 0, stream>>>(feat, featb);
    cvt_w_kernel<<<(D * D + 255) / 256, 256, 0, stream>>>(Wn, Wself, wnb, wsb);
    hist_kernel<<<(N_EDGES + 255) / 256, 256, 0, stream>>>(dst, hist);
    scan1_kernel<<<NB, 256, 0, stream>>>(hist, cursor, bsum);
    scan2_kernel<<<1, 256, 0, stream>>>(bsum);
    addoff_kernel<<<NB, 256, 0, stream>>>(cursor, bsum);
    fill_kernel<<<(N_EDGES + 255) / 256, 256, 0, stream>>>(src, dst, cursor, esrc);
    gather_kernel<<<(N_NODES + 3) / 4, 256, 0, stream>>>(featb, cursor, hist, esrc, aggb);
    mfma_epi_kernel<<<(N_NODES / 16 + 3) / 4, 256, 0, stream>>>(featb, aggb, wsb, wnb, bself, out);
}